// Round 1
// baseline (278.643 us; speedup 1.0000x reference)
//
#include <hip/hip_runtime.h>

// Soft cross-entropy: per token t (n=131072, K=256):
//   loss_t = lse_t * sum(targ_t) - dot(targ_t, x_t),  lse = m + log(sum exp(x-m))
// out = mean(loss_t * mask_t)
//
// One 64-lane wave per token: lane i holds float4 x[4i..4i+3], targ[4i..4i+3]
// (64 lanes * 16B = 1KiB = exactly one K=256 fp32 row, fully coalesced).

__global__ __launch_bounds__(256) void sxent_partial_kernel(
    const float* __restrict__ input,
    const float* __restrict__ target,
    const float* __restrict__ mask,
    float* __restrict__ partials,
    int n_tokens)
{
    const int lane  = threadIdx.x & 63;
    const int wave  = threadIdx.x >> 6;          // 0..3
    const int wpb   = blockDim.x >> 6;           // waves per block = 4
    const int gwave = blockIdx.x * wpb + wave;
    const int nwave = gridDim.x * wpb;

    float acc = 0.0f;

    for (int t = gwave; t < n_tokens; t += nwave) {
        const float4 x = ((const float4*)(input  + (size_t)t * 256))[lane];
        const float4 g = ((const float4*)(target + (size_t)t * 256))[lane];

        // ---- wave-wide max of x ----
        float m = fmaxf(fmaxf(x.x, x.y), fmaxf(x.z, x.w));
        #pragma unroll
        for (int off = 32; off >= 1; off >>= 1)
            m = fmaxf(m, __shfl_xor(m, off, 64));

        // ---- lane-local partial sums ----
        float se  = __expf(x.x - m) + __expf(x.y - m)
                  + __expf(x.z - m) + __expf(x.w - m);
        float dot = g.x * x.x + g.y * x.y + g.z * x.z + g.w * x.w;
        float st  = g.x + g.y + g.z + g.w;

        // ---- wave-wide sums (butterfly, all lanes end with total) ----
        #pragma unroll
        for (int off = 32; off >= 1; off >>= 1) {
            se  += __shfl_xor(se,  off, 64);
            dot += __shfl_xor(dot, off, 64);
            st  += __shfl_xor(st,  off, 64);
        }

        if (lane == 0) {
            float lse  = m + __logf(se);
            acc += (lse * st - dot) * mask[t];
        }
    }

    __shared__ float lds[4];
    if (lane == 0) lds[wave] = acc;
    __syncthreads();
    if (threadIdx.x == 0) {
        float s = 0.0f;
        for (int w = 0; w < wpb; ++w) s += lds[w];
        partials[blockIdx.x] = s;   // plain store: overwrites 0xAA poison
    }
}

__global__ __launch_bounds__(256) void sxent_final_kernel(
    const float* __restrict__ partials, int n_partials,
    float* __restrict__ out, float inv_n)
{
    float s = 0.0f;
    for (int i = threadIdx.x; i < n_partials; i += blockDim.x)
        s += partials[i];

    __shared__ float lds[256];
    lds[threadIdx.x] = s;
    __syncthreads();
    #pragma unroll
    for (int stride = 128; stride >= 1; stride >>= 1) {
        if (threadIdx.x < stride) lds[threadIdx.x] += lds[threadIdx.x + stride];
        __syncthreads();
    }
    if (threadIdx.x == 0) out[0] = lds[0] * inv_n;
}

extern "C" void kernel_launch(void* const* d_in, const int* in_sizes, int n_in,
                              void* d_out, int out_size, void* d_ws, size_t ws_size,
                              hipStream_t stream) {
    const float* input  = (const float*)d_in[0];   // [B,S,K] fp32
    const float* target = (const float*)d_in[1];   // [B,S,K] fp32
    const float* mask   = (const float*)d_in[2];   // [B,S]   fp32
    float* out      = (float*)d_out;
    float* partials = (float*)d_ws;                // one float per block

    const int n_tokens = in_sizes[2];              // B*S = 131072 (K fixed at 256)
    const int blocks   = 2048;                     // 2048 blk * 4 waves = 8192 waves

    sxent_partial_kernel<<<blocks, 256, 0, stream>>>(input, target, mask,
                                                     partials, n_tokens);
    sxent_final_kernel<<<1, 256, 0, stream>>>(partials, blocks, out,
                                              1.0f / (float)n_tokens);
}